// Round 2
// baseline (321.518 us; speedup 1.0000x reference)
//
#include <hip/hip_runtime.h>
#include <stdint.h>

#define CHUNKS 16
#define STATE_SZ 16512              // 128*128 + 128 floats per (bh, chunk)
#define SMEM_BYTES 64384

typedef __attribute__((ext_vector_type(8))) short bf16x8;
typedef __attribute__((ext_vector_type(4))) short bf16x4;
typedef __attribute__((ext_vector_type(4))) float f32x4;

__device__ inline uint16_t f2bf(float f) {
    uint32_t x = __builtin_bit_cast(uint32_t, f);
    x += 0x7fffu + ((x >> 16) & 1u);
    return (uint16_t)(x >> 16);
}
__device__ inline uint32_t pack2(float a, float b) {
    return (uint32_t)f2bf(a) | ((uint32_t)f2bf(b) << 16);
}
__device__ inline float bflo(uint32_t w){ return __builtin_bit_cast(float, w << 16); }
__device__ inline float bfhi(uint32_t w){ return __builtin_bit_cast(float, w & 0xffff0000u); }

// phi(x) = clip(elu(x*s+b)+1, 0, 10) = (y>0) ? min(y+1,10) : exp(y)
__device__ inline float phi_f(float x, float s, float b) {
    float y = fmaf(x, s, b);
    float pos = fminf(y + 1.0f, 10.0f);
    float neg = __expf(y);
    return (y > 0.0f) ? pos : neg;
}

__device__ inline void ld8(float* d, const float* p) {
    float4 a = *(const float4*)p;
    float4 b = *(const float4*)(p + 4);
    d[0]=a.x; d[1]=a.y; d[2]=a.z; d[3]=a.w;
    d[4]=b.x; d[5]=b.y; d[6]=b.z; d[7]=b.w;
}

// In-wave 4x128 transpose. Input: lane holds packed col-pairs p0..p3 of row sr=4w+(lane>>4),
// cols sc..sc+7 (sc=8*(lane&15)). Output: lane gets rows 4w..4w+3 of col 2*lane (lo) and
// 2*lane+1 (hi), packed two rows per uint32; z0/z1 = column sums over the 4 rows.
__device__ inline void xpose4(uint32_t p0, uint32_t p1, uint32_t p2, uint32_t p3,
                              int lane, uint2& lo, uint2& hi, float& z0, float& z1) {
    const int sb = lane >> 2;
    const int e0 = lane & 1, e1 = lane & 2;
    uint32_t w[4];
    #pragma unroll
    for (int j = 0; j < 4; ++j) {
        int src = 16*j + sb;
        uint32_t t0 = (uint32_t)__shfl((int)p0, src, 64);
        uint32_t t1 = (uint32_t)__shfl((int)p1, src, 64);
        uint32_t t2 = (uint32_t)__shfl((int)p2, src, 64);
        uint32_t t3 = (uint32_t)__shfl((int)p3, src, 64);
        uint32_t a = e0 ? t1 : t0;
        uint32_t b = e0 ? t3 : t2;
        w[j] = e1 ? b : a;
    }
    lo.x = (w[0] & 0xffffu) | (w[1] << 16);
    lo.y = (w[2] & 0xffffu) | (w[3] << 16);
    hi.x = (w[0] >> 16) | (w[1] & 0xffff0000u);
    hi.y = (w[2] >> 16) | (w[3] & 0xffff0000u);
    z0 = bflo(w[0]) + bflo(w[1]) + bflo(w[2]) + bflo(w[3]);
    z1 = bfhi(w[0]) + bfhi(w[1]) + bfhi(w[2]) + bfhi(w[3]);
}

// pkT/vT: [128 rows][36 u16] (32 payload + 4 pad). 8 slots of 4 elems, physical
// slot = (logical + (row>>3)) & 7  -> transpose writes are <=2-way, frag reads free.
__device__ inline bf16x8 fragT(const uint16_t* T, int row, int q4) {
    const int key = row >> 3;
    const bf16x4 lo = *(const bf16x4*)&T[row*36 + 4*((2*q4     + key) & 7)];
    const bf16x4 hi = *(const bf16x4*)&T[row*36 + 4*((2*q4 + 1 + key) & 7)];
    bf16x8 r;
    r[0]=lo[0]; r[1]=lo[1]; r[2]=lo[2]; r[3]=lo[3];
    r[4]=hi[0]; r[5]=hi[1]; r[6]=hi[2]; r[7]=hi[3];
    return r;
}

__device__ inline void xpose_store(uint16_t* T, uint32_t p0, uint32_t p1, uint32_t p2,
                                   uint32_t p3, int lane, int slot8, float* zp, int wv) {
    uint2 lo, hi; float z0, z1;
    xpose4(p0, p1, p2, p3, lane, lo, hi, z0, z1);
    *(uint2*)&T[(2*lane)*36   + 4*slot8] = lo;
    *(uint2*)&T[(2*lane+1)*36 + 4*slot8] = hi;
    if (zp) { zp[wv*128 + 2*lane] = z0; zp[wv*128 + 2*lane + 1] = z1; }
}

// LDS layout (bytes):
//   pkT     [0, 9216)      128 x 36 u16
//   vT      [9216, 18432)  128 x 36 u16
//   S_bfT   [18432, 51200) 128 x 128 u16, slot-rotated by row (32 slots of 4)
//   pq_bf   [51200, 59648) 32 x 132 u16
//   Zpart   [59648, 63744) 8 x 128 f32
//   Zl      [63744, 64256) 128 f32
//   inv_den [64256, 64384) 32 f32
template<bool PHASE2>
__global__ __launch_bounds__(512, 4) void la_phase(
    const float* __restrict__ Q, const float* __restrict__ K,
    const float* __restrict__ V, const float* __restrict__ scale,
    const float* __restrict__ bias, float* __restrict__ states,
    float* __restrict__ out)
{
    extern __shared__ char smem[];
    uint16_t* pkT     = (uint16_t*)(smem);
    uint16_t* vT      = (uint16_t*)(smem + 9216);
    uint16_t* S_bfT   = (uint16_t*)(smem + 18432);
    uint16_t* pq_bf   = (uint16_t*)(smem + 51200);
    float*    Zpart   = (float*)(smem + 59648);
    float*    Zl      = (float*)(smem + 63744);
    float*    inv_den = (float*)(smem + 64256);

    const int tid  = threadIdx.x;
    const int bh   = blockIdx.x >> 4;
    const int ch   = blockIdx.x & 15;
    const int lane = tid & 63;
    const int wv   = tid >> 6;
    const int i15  = lane & 15;
    const int q4   = lane >> 4;
    const int sr   = tid >> 4;
    const int sc   = (tid & 15) * 8;
    const int slot8 = (wv + (lane >> 2)) & 7;

    const size_t base = (size_t)bh * 4096 * 128;
    const int h = bh & 15;

    float sreg[8], breg[8];
    #pragma unroll
    for (int j = 0; j < 8; ++j) {
        sreg[j] = scale[h*128 + sc + j];
        breg[j] = bias[h*128 + sc + j];
    }

    float* stb = states + (size_t)(bh*CHUNKS + ch) * STATE_SZ;

    f32x4 accS[8];
    if (PHASE2) {
        #pragma unroll
        for (int mt = 0; mt < 8; ++mt) {
            float4 t = *(const float4*)(stb + wv*2048 + mt*256 + lane*4);
            accS[mt] = (f32x4){t.x, t.y, t.z, t.w};
        }
        if (tid < 128) Zl[tid] = stb[16384 + tid];
    } else {
        #pragma unroll
        for (int mt = 0; mt < 8; ++mt) accS[mt] = (f32x4){0.f, 0.f, 0.f, 0.f};
        if (tid < 128) Zl[tid] = 0.f;
    }

    // ---------- prologue: block 0 ----------
    float kr[8], vr[8], qr[8], fq[8];
    {
        const size_t ro = base + (size_t)((ch*8)*32 + sr) * 128 + sc;
        ld8(kr, K + ro);
        ld8(vr, V + ro);
        if (PHASE2) ld8(qr, Q + ro);
    }
    {
        uint32_t pk0 = pack2(phi_f(kr[0],sreg[0],breg[0]), phi_f(kr[1],sreg[1],breg[1]));
        uint32_t pk1 = pack2(phi_f(kr[2],sreg[2],breg[2]), phi_f(kr[3],sreg[3],breg[3]));
        uint32_t pk2 = pack2(phi_f(kr[4],sreg[4],breg[4]), phi_f(kr[5],sreg[5],breg[5]));
        uint32_t pk3 = pack2(phi_f(kr[6],sreg[6],breg[6]), phi_f(kr[7],sreg[7],breg[7]));
        xpose_store(pkT, pk0, pk1, pk2, pk3, lane, slot8, Zpart, wv);
        uint32_t pv0 = pack2(vr[0], vr[1]);
        uint32_t pv1 = pack2(vr[2], vr[3]);
        uint32_t pv2 = pack2(vr[4], vr[5]);
        uint32_t pv3 = pack2(vr[6], vr[7]);
        xpose_store(vT, pv0, pv1, pv2, pv3, lane, slot8, (float*)0, wv);
    }
    if (PHASE2) {
        uint32_t hq[4];
        #pragma unroll
        for (int j = 0; j < 4; ++j) {
            hq[j] = pack2(phi_f(qr[2*j],   sreg[2*j],   breg[2*j]),
                          phi_f(qr[2*j+1], sreg[2*j+1], breg[2*j+1]));
            fq[2*j]   = bflo(hq[j]);
            fq[2*j+1] = bfhi(hq[j]);
        }
        *(uint2*)&pq_bf[sr*132 + sc]     = (uint2){hq[0], hq[1]};
        *(uint2*)&pq_bf[sr*132 + sc + 4] = (uint2){hq[2], hq[3]};
    }
    __syncthreads();   // alpha(0)

    float o8[8];
    #pragma unroll 1
    for (int i = 0; i < 8; ++i) {
        // ================= Seg1(i) =================
        if (PHASE2 && i > 0) {
            // stage pq(i) from qr (loaded last iteration); keep bf16-quantized fq for den
            uint32_t hq[4];
            #pragma unroll
            for (int j = 0; j < 4; ++j) {
                hq[j] = pack2(phi_f(qr[2*j],   sreg[2*j],   breg[2*j]),
                              phi_f(qr[2*j+1], sreg[2*j+1], breg[2*j+1]));
                fq[2*j]   = bflo(hq[j]);
                fq[2*j+1] = bfhi(hq[j]);
            }
            *(uint2*)&pq_bf[sr*132 + sc]     = (uint2){hq[0], hq[1]};
            *(uint2*)&pq_bf[sr*132 + sc + 4] = (uint2){hq[2], hq[3]};
        }
        if (i < 7) {   // prefetch block i+1
            const size_t ro = base + (size_t)((ch*8 + i + 1)*32 + sr) * 128 + sc;
            ld8(kr, K + ro);
            ld8(vr, V + ro);
            if (PHASE2) ld8(qr, Q + ro);
        }
        // S-update MFMAs: S[d][e] += sum_r phiK[r][d] * V[r][e]
        {
            bf16x8 bv = fragT(vT, 16*wv + i15, q4);
            #pragma unroll
            for (int mt = 0; mt < 8; ++mt) {
                bf16x8 av = fragT(pkT, 16*mt + i15, q4);
                accS[mt] = __builtin_amdgcn_mfma_f32_16x16x32_bf16(av, bv, accS[mt], 0, 0, 0);
            }
        }
        // Z update
        if (tid < 128) {
            float z = Zl[tid];
            #pragma unroll
            for (int g = 0; g < 8; ++g) z += Zpart[g*128 + tid];
            Zl[tid] = z;
        }
        if (PHASE2) {
            // S -> bf16 LDS (own regs, slot-rotated)
            const int e = 16*wv + i15;
            #pragma unroll
            for (int mt = 0; mt < 8; ++mt) {
                uint2 o;
                o.x = pack2(accS[mt][0], accS[mt][1]);
                o.y = pack2(accS[mt][2], accS[mt][3]);
                const int ps = (4*mt + q4 + e) & 31;
                *(uint2*)&S_bfT[e*128 + 4*ps] = o;
            }
            if (i > 0) {   // epilogue for block i-1
                const int blk = ch*8 + i - 1;
                #pragma unroll
                for (int qt = 0; qt < 2; ++qt)
                #pragma unroll
                for (int r = 0; r < 4; ++r) {
                    const int qrow = 16*qt + 4*q4 + r;
                    out[base + (size_t)(blk*32 + qrow)*128 + 16*wv + i15] =
                        o8[qt*4 + r] * inv_den[qrow];
                }
            }
        }
        __syncthreads();   // beta(i)
        // ================= Seg2(i) =================
        if (PHASE2) {
            f32x4 acc2[2];
            acc2[0] = (f32x4){0.f, 0.f, 0.f, 0.f};
            acc2[1] = (f32x4){0.f, 0.f, 0.f, 0.f};
            const int eb = 16*wv + i15;
            #pragma unroll
            for (int ks = 0; ks < 4; ++ks) {
                const int p0 = (8*ks + 2*q4 + eb) & 31;
                const bf16x4 slo = *(const bf16x4*)&S_bfT[eb*128 + 4*p0];
                const bf16x4 shi = *(const bf16x4*)&S_bfT[eb*128 + 4*((p0 + 1) & 31)];
                bf16x8 sb;
                sb[0]=slo[0]; sb[1]=slo[1]; sb[2]=slo[2]; sb[3]=slo[3];
                sb[4]=shi[0]; sb[5]=shi[1]; sb[6]=shi[2]; sb[7]=shi[3];
                #pragma unroll
                for (int qt = 0; qt < 2; ++qt) {
                    const int qr0 = 16*qt + i15;
                    const bf16x4 qlo = *(const bf16x4*)&pq_bf[qr0*132 + 32*ks + 8*q4];
                    const bf16x4 qhi = *(const bf16x4*)&pq_bf[qr0*132 + 32*ks + 8*q4 + 4];
                    bf16x8 qa;
                    qa[0]=qlo[0]; qa[1]=qlo[1]; qa[2]=qlo[2]; qa[3]=qlo[3];
                    qa[4]=qhi[0]; qa[5]=qhi[1]; qa[6]=qhi[2]; qa[7]=qhi[3];
                    acc2[qt] = __builtin_amdgcn_mfma_f32_16x16x32_bf16(qa, sb, acc2[qt], 0, 0, 0);
                }
            }
            // den via register partials + 16-lane shuffle reduce
            float4 za = *(const float4*)&Zl[sc];
            float4 zb = *(const float4*)&Zl[sc + 4];
            float sden = fq[0]*za.x + fq[1]*za.y + fq[2]*za.z + fq[3]*za.w
                       + fq[4]*zb.x + fq[5]*zb.y + fq[6]*zb.z + fq[7]*zb.w;
            sden += __shfl_xor(sden, 1, 64);
            sden += __shfl_xor(sden, 2, 64);
            sden += __shfl_xor(sden, 4, 64);
            sden += __shfl_xor(sden, 8, 64);
            if ((tid & 15) == 0) inv_den[sr] = 1.0f / fmaxf(sden, 1e-6f);
            #pragma unroll
            for (int qt = 0; qt < 2; ++qt)
            #pragma unroll
            for (int r = 0; r < 4; ++r) o8[qt*4 + r] = acc2[qt][r];
        }
        if (i < 7) {   // register-transpose block i+1 into pkT/vT (+ Zpart)
            uint32_t pk0 = pack2(phi_f(kr[0],sreg[0],breg[0]), phi_f(kr[1],sreg[1],breg[1]));
            uint32_t pk1 = pack2(phi_f(kr[2],sreg[2],breg[2]), phi_f(kr[3],sreg[3],breg[3]));
            uint32_t pk2 = pack2(phi_f(kr[4],sreg[4],breg[4]), phi_f(kr[5],sreg[5],breg[5]));
            uint32_t pk3 = pack2(phi_f(kr[6],sreg[6],breg[6]), phi_f(kr[7],sreg[7],breg[7]));
            xpose_store(pkT, pk0, pk1, pk2, pk3, lane, slot8, Zpart, wv);
            uint32_t pv0 = pack2(vr[0], vr[1]);
            uint32_t pv1 = pack2(vr[2], vr[3]);
            uint32_t pv2 = pack2(vr[4], vr[5]);
            uint32_t pv3 = pack2(vr[6], vr[7]);
            xpose_store(vT, pv0, pv1, pv2, pv3, lane, slot8, (float*)0, wv);
        }
        __syncthreads();   // alpha(i+1)
    }

    if (PHASE2) {
        const int blk = ch*8 + 7;
        #pragma unroll
        for (int qt = 0; qt < 2; ++qt)
        #pragma unroll
        for (int r = 0; r < 4; ++r) {
            const int qrow = 16*qt + 4*q4 + r;
            out[base + (size_t)(blk*32 + qrow)*128 + 16*wv + i15] =
                o8[qt*4 + r] * inv_den[qrow];
        }
    } else {
        // coalesced state store: [wv][mt][lane] float4
        #pragma unroll
        for (int mt = 0; mt < 8; ++mt) {
            float4 t = {accS[mt][0], accS[mt][1], accS[mt][2], accS[mt][3]};
            *(float4*)(stb + wv*2048 + mt*256 + lane*4) = t;
        }
        if (tid < 128) stb[16384 + tid] = Zl[tid];
    }
}

// Exclusive prefix over the 16 chunk states per chain; one thread per element column.
// Loads all 16 first (independent, full MLP), scans in registers, stores.
__global__ __launch_bounds__(256) void la_prefix(float* __restrict__ states) {
    const int gid = blockIdx.x * 256 + threadIdx.x;    // 0 .. 32*16512-1
    const int bh  = gid / STATE_SZ;
    const int e   = gid - bh * STATE_SZ;
    float* p = states + (size_t)bh * CHUNKS * STATE_SZ + e;
    float v[CHUNKS];
    #pragma unroll
    for (int c = 0; c < CHUNKS; ++c) v[c] = p[c * STATE_SZ];
    float run = 0.f;
    #pragma unroll
    for (int c = 0; c < CHUNKS; ++c) { p[c * STATE_SZ] = run; run += v[c]; }
}

extern "C" void kernel_launch(void* const* d_in, const int* in_sizes, int n_in,
                              void* d_out, int out_size, void* d_ws, size_t ws_size,
                              hipStream_t stream) {
    const float* Q     = (const float*)d_in[0];
    const float* K     = (const float*)d_in[1];
    const float* V     = (const float*)d_in[2];
    const float* scale = (const float*)d_in[3];
    const float* bias  = (const float*)d_in[4];
    float* out    = (float*)d_out;
    float* states = (float*)d_ws;   // 32*16*16512*4 = 33.8 MB

    hipLaunchKernelGGL((la_phase<false>), dim3(512), dim3(512), SMEM_BYTES, stream,
                       Q, K, V, scale, bias, states, out);
    hipLaunchKernelGGL(la_prefix, dim3((32*STATE_SZ)/256), dim3(256), 0, stream, states);
    hipLaunchKernelGGL((la_phase<true>), dim3(512), dim3(512), SMEM_BYTES, stream,
                       Q, K, V, scale, bias, states, out);
}

// Round 3
// 296.205 us; speedup vs baseline: 1.0855x; 1.0855x over previous
//
#include <hip/hip_runtime.h>
#include <stdint.h>

#define CHUNKS 16
#define STATE_SZ 16512              // 128*128 + 128 floats per (bh, chunk)
#define SMEM_BYTES 64384

typedef __attribute__((ext_vector_type(8))) short bf16x8;
typedef __attribute__((ext_vector_type(4))) short bf16x4;
typedef __attribute__((ext_vector_type(4))) float f32x4;

__device__ inline uint16_t f2bf(float f) {
    uint32_t x = __builtin_bit_cast(uint32_t, f);
    x += 0x7fffu + ((x >> 16) & 1u);
    return (uint16_t)(x >> 16);
}
__device__ inline uint32_t pack2(float a, float b) {
    return (uint32_t)f2bf(a) | ((uint32_t)f2bf(b) << 16);
}
__device__ inline float bflo(uint32_t w){ return __builtin_bit_cast(float, w << 16); }
__device__ inline float bfhi(uint32_t w){ return __builtin_bit_cast(float, w & 0xffff0000u); }

// phi(x) = clip(elu(x*s+b)+1, 0, 10) = (y>0) ? min(y+1,10) : exp(y)
__device__ inline float phi_f(float x, float s, float b) {
    float y = fmaf(x, s, b);
    float pos = fminf(y + 1.0f, 10.0f);
    float neg = __expf(y);
    return (y > 0.0f) ? pos : neg;
}

// load 8 floats and pack to 4 uint32 of bf16 pairs, applying phi if S!=0
__device__ inline void ld8_phi(uint32_t* p, const float* gp, const float* s, const float* b) {
    float4 a0 = *(const float4*)gp;
    float4 a1 = *(const float4*)(gp + 4);
    float f[8] = {a0.x,a0.y,a0.z,a0.w,a1.x,a1.y,a1.z,a1.w};
    #pragma unroll
    for (int j = 0; j < 4; ++j)
        p[j] = pack2(phi_f(f[2*j], s[2*j], b[2*j]), phi_f(f[2*j+1], s[2*j+1], b[2*j+1]));
}
__device__ inline void ld8_bf(uint32_t* p, const float* gp) {
    float4 a0 = *(const float4*)gp;
    float4 a1 = *(const float4*)(gp + 4);
    float f[8] = {a0.x,a0.y,a0.z,a0.w,a1.x,a1.y,a1.z,a1.w};
    #pragma unroll
    for (int j = 0; j < 4; ++j) p[j] = pack2(f[2*j], f[2*j+1]);
}

// In-wave 4x128 transpose. Input: lane holds packed col-pairs p0..p3 of row sr=4w+(lane>>4),
// cols sc..sc+7 (sc=8*(lane&15)). Output: lane gets rows 4w..4w+3 of col 2*lane (lo) and
// 2*lane+1 (hi), packed two rows per uint32; z0/z1 = column sums over the 4 rows.
__device__ inline void xpose4(uint32_t p0, uint32_t p1, uint32_t p2, uint32_t p3,
                              int lane, uint2& lo, uint2& hi, float& z0, float& z1) {
    const int sb = lane >> 2;
    const int e0 = lane & 1, e1 = lane & 2;
    uint32_t w[4];
    #pragma unroll
    for (int j = 0; j < 4; ++j) {
        int src = 16*j + sb;
        uint32_t t0 = (uint32_t)__shfl((int)p0, src, 64);
        uint32_t t1 = (uint32_t)__shfl((int)p1, src, 64);
        uint32_t t2 = (uint32_t)__shfl((int)p2, src, 64);
        uint32_t t3 = (uint32_t)__shfl((int)p3, src, 64);
        uint32_t a = e0 ? t1 : t0;
        uint32_t b = e0 ? t3 : t2;
        w[j] = e1 ? b : a;
    }
    lo.x = (w[0] & 0xffffu) | (w[1] << 16);
    lo.y = (w[2] & 0xffffu) | (w[3] << 16);
    hi.x = (w[0] >> 16) | (w[1] & 0xffff0000u);
    hi.y = (w[2] >> 16) | (w[3] & 0xffff0000u);
    z0 = bflo(w[0]) + bflo(w[1]) + bflo(w[2]) + bflo(w[3]);
    z1 = bfhi(w[0]) + bfhi(w[1]) + bfhi(w[2]) + bfhi(w[3]);
}

// pkT/vT: [128 rows][36 u16] (32 payload + 4 pad). 8 slots of 4 elems, physical
// slot = (logical + (row>>3)) & 7  -> transpose writes are <=2-way, frag reads free.
__device__ inline bf16x8 fragT(const uint16_t* T, int row, int q4) {
    const int key = row >> 3;
    const bf16x4 lo = *(const bf16x4*)&T[row*36 + 4*((2*q4     + key) & 7)];
    const bf16x4 hi = *(const bf16x4*)&T[row*36 + 4*((2*q4 + 1 + key) & 7)];
    bf16x8 r;
    r[0]=lo[0]; r[1]=lo[1]; r[2]=lo[2]; r[3]=lo[3];
    r[4]=hi[0]; r[5]=hi[1]; r[6]=hi[2]; r[7]=hi[3];
    return r;
}

__device__ inline void xpose_store(uint16_t* T, const uint32_t* p,
                                   int lane, int slot8, float* zp, int wv) {
    uint2 lo, hi; float z0, z1;
    xpose4(p[0], p[1], p[2], p[3], lane, lo, hi, z0, z1);
    *(uint2*)&T[(2*lane)*36   + 4*slot8] = lo;
    *(uint2*)&T[(2*lane+1)*36 + 4*slot8] = hi;
    if (zp) { zp[wv*128 + 2*lane] = z0; zp[wv*128 + 2*lane + 1] = z1; }
}

// LDS layout (bytes):
//   pkT     [0, 9216)      128 x 36 u16
//   vT      [9216, 18432)  128 x 36 u16
//   S_bfT   [18432, 51200) 128 x 128 u16, slot-rotated by row (32 slots of 4)
//   pq_bf   [51200, 59648) 32 x 132 u16
//   Zpart   [59648, 63744) 8 x 128 f32
//   Zl      [63744, 64256) 128 f32
//   inv_den [64256, 64384) 32 f32
template<bool PHASE2>
__global__ __launch_bounds__(512)
__attribute__((amdgpu_waves_per_eu(4, 4)))
void la_phase(
    const float* __restrict__ Q, const float* __restrict__ K,
    const float* __restrict__ V, const float* __restrict__ scale,
    const float* __restrict__ bias, float* __restrict__ states,
    float* __restrict__ out)
{
    __shared__ __align__(16) char smem[SMEM_BYTES];
    uint16_t* pkT     = (uint16_t*)(smem);
    uint16_t* vT      = (uint16_t*)(smem + 9216);
    uint16_t* S_bfT   = (uint16_t*)(smem + 18432);
    uint16_t* pq_bf   = (uint16_t*)(smem + 51200);
    float*    Zpart   = (float*)(smem + 59648);
    float*    Zl      = (float*)(smem + 63744);
    float*    inv_den = (float*)(smem + 64256);

    const int tid  = threadIdx.x;
    const int bh   = blockIdx.x >> 4;
    const int ch   = blockIdx.x & 15;
    const int lane = tid & 63;
    const int wv   = tid >> 6;
    const int i15  = lane & 15;
    const int q4   = lane >> 4;
    const int sr   = tid >> 4;
    const int sc   = (tid & 15) * 8;
    const int slot8 = (wv + (lane >> 2)) & 7;

    const size_t base = (size_t)bh * 4096 * 128;
    const int h = bh & 15;

    float sreg[8], breg[8];
    #pragma unroll
    for (int j = 0; j < 8; ++j) {
        sreg[j] = scale[h*128 + sc + j];
        breg[j] = bias[h*128 + sc + j];
    }

    float* stb = states + (size_t)(bh*CHUNKS + ch) * STATE_SZ;

    f32x4 accS[8];
    if (PHASE2) {
        #pragma unroll
        for (int mt = 0; mt < 8; ++mt) {
            float4 t = *(const float4*)(stb + wv*2048 + mt*256 + lane*4);
            accS[mt] = (f32x4){t.x, t.y, t.z, t.w};
        }
        if (tid < 128) Zl[tid] = stb[16384 + tid];
    } else {
        #pragma unroll
        for (int mt = 0; mt < 8; ++mt) accS[mt] = (f32x4){0.f, 0.f, 0.f, 0.f};
        if (tid < 128) Zl[tid] = 0.f;
    }

    // ---------- prologue: block 0 ----------
    uint32_t pkp[4], pvp[4], hq[4];
    {
        const size_t ro = base + (size_t)((ch*8)*32 + sr) * 128 + sc;
        ld8_phi(pkp, K + ro, sreg, breg);
        ld8_bf (pvp, V + ro);
        xpose_store(pkT, pkp, lane, slot8, Zpart, wv);
        xpose_store(vT,  pvp, lane, slot8, (float*)0, wv);
        if (PHASE2) {
            ld8_phi(hq, Q + ro, sreg, breg);
            *(uint2*)&pq_bf[sr*132 + sc]     = (uint2){hq[0], hq[1]};
            *(uint2*)&pq_bf[sr*132 + sc + 4] = (uint2){hq[2], hq[3]};
        }
    }
    __syncthreads();   // alpha(0)

    float o8[8];
    #pragma unroll 1
    for (int i = 0; i < 8; ++i) {
        // ================= Seg1(i) =================
        if (PHASE2 && i > 0) {
            // stage pq(i) (converted during iteration i-1)
            *(uint2*)&pq_bf[sr*132 + sc]     = (uint2){hq[0], hq[1]};
            *(uint2*)&pq_bf[sr*132 + sc + 4] = (uint2){hq[2], hq[3]};
        }
        // S-update MFMAs: S[d][e] += sum_r phiK[r][d] * V[r][e]
        {
            bf16x8 bv = fragT(vT, 16*wv + i15, q4);
            #pragma unroll
            for (int mt = 0; mt < 8; ++mt) {
                bf16x8 av = fragT(pkT, 16*mt + i15, q4);
                accS[mt] = __builtin_amdgcn_mfma_f32_16x16x32_bf16(av, bv, accS[mt], 0, 0, 0);
            }
        }
        if (i < 7) {   // load + convert block i+1 (packed regs only live past here)
            const size_t ro = base + (size_t)((ch*8 + i + 1)*32 + sr) * 128 + sc;
            ld8_phi(pkp, K + ro, sreg, breg);
            ld8_bf (pvp, V + ro);
            if (PHASE2) ld8_phi(hq, Q + ro, sreg, breg);
        }
        // Z update
        if (tid < 128) {
            float z = Zl[tid];
            #pragma unroll
            for (int g = 0; g < 8; ++g) z += Zpart[g*128 + tid];
            Zl[tid] = z;
        }
        if (PHASE2) {
            // S -> bf16 LDS (own regs, slot-rotated)
            const int e = 16*wv + i15;
            #pragma unroll
            for (int mt = 0; mt < 8; ++mt) {
                uint2 o;
                o.x = pack2(accS[mt][0], accS[mt][1]);
                o.y = pack2(accS[mt][2], accS[mt][3]);
                const int ps = (4*mt + q4 + e) & 31;
                *(uint2*)&S_bfT[e*128 + 4*ps] = o;
            }
            if (i > 0) {   // epilogue for block i-1
                const int blk = ch*8 + i - 1;
                #pragma unroll
                for (int qt = 0; qt < 2; ++qt)
                #pragma unroll
                for (int r = 0; r < 4; ++r) {
                    const int qrow = 16*qt + 4*q4 + r;
                    out[base + (size_t)(blk*32 + qrow)*128 + 16*wv + i15] =
                        o8[qt*4 + r] * inv_den[qrow];
                }
            }
        }
        __syncthreads();   // beta(i)
        // ================= Seg2(i) =================
        if (PHASE2) {
            f32x4 acc2[2];
            acc2[0] = (f32x4){0.f, 0.f, 0.f, 0.f};
            acc2[1] = (f32x4){0.f, 0.f, 0.f, 0.f};
            const int eb = 16*wv + i15;
            #pragma unroll
            for (int ks = 0; ks < 4; ++ks) {
                const int p0 = (8*ks + 2*q4 + eb) & 31;
                const bf16x4 slo = *(const bf16x4*)&S_bfT[eb*128 + 4*p0];
                const bf16x4 shi = *(const bf16x4*)&S_bfT[eb*128 + 4*((p0 + 1) & 31)];
                bf16x8 sb;
                sb[0]=slo[0]; sb[1]=slo[1]; sb[2]=slo[2]; sb[3]=slo[3];
                sb[4]=shi[0]; sb[5]=shi[1]; sb[6]=shi[2]; sb[7]=shi[3];
                #pragma unroll
                for (int qt = 0; qt < 2; ++qt) {
                    const int qr0 = 16*qt + i15;
                    const bf16x4 qlo = *(const bf16x4*)&pq_bf[qr0*132 + 32*ks + 8*q4];
                    const bf16x4 qhi = *(const bf16x4*)&pq_bf[qr0*132 + 32*ks + 8*q4 + 4];
                    bf16x8 qa;
                    qa[0]=qlo[0]; qa[1]=qlo[1]; qa[2]=qlo[2]; qa[3]=qlo[3];
                    qa[4]=qhi[0]; qa[5]=qhi[1]; qa[6]=qhi[2]; qa[7]=qhi[3];
                    acc2[qt] = __builtin_amdgcn_mfma_f32_16x16x32_bf16(qa, sb, acc2[qt], 0, 0, 0);
                }
            }
            // den: read own staged pq row-segment back from LDS (same bf16 values
            // the num MFMA consumed -> rounding cancels in num/den)
            {
                uint2 w0 = *(const uint2*)&pq_bf[sr*132 + sc];
                uint2 w1 = *(const uint2*)&pq_bf[sr*132 + sc + 4];
                float4 za = *(const float4*)&Zl[sc];
                float4 zb = *(const float4*)&Zl[sc + 4];
                float sden = bflo(w0.x)*za.x + bfhi(w0.x)*za.y
                           + bflo(w0.y)*za.z + bfhi(w0.y)*za.w
                           + bflo(w1.x)*zb.x + bfhi(w1.x)*zb.y
                           + bflo(w1.y)*zb.z + bfhi(w1.y)*zb.w;
                sden += __shfl_xor(sden, 1, 64);
                sden += __shfl_xor(sden, 2, 64);
                sden += __shfl_xor(sden, 4, 64);
                sden += __shfl_xor(sden, 8, 64);
                if ((tid & 15) == 0) inv_den[sr] = 1.0f / fmaxf(sden, 1e-6f);
            }
            #pragma unroll
            for (int qt = 0; qt < 2; ++qt)
            #pragma unroll
            for (int r = 0; r < 4; ++r) o8[qt*4 + r] = acc2[qt][r];
        }
        if (i < 7) {   // register-transpose block i+1 into pkT/vT (+ Zpart)
            xpose_store(pkT, pkp, lane, slot8, Zpart, wv);
            xpose_store(vT,  pvp, lane, slot8, (float*)0, wv);
        }
        __syncthreads();   // alpha(i+1)
    }

    if (PHASE2) {
        const int blk = ch*8 + 7;
        #pragma unroll
        for (int qt = 0; qt < 2; ++qt)
        #pragma unroll
        for (int r = 0; r < 4; ++r) {
            const int qrow = 16*qt + 4*q4 + r;
            out[base + (size_t)(blk*32 + qrow)*128 + 16*wv + i15] =
                o8[qt*4 + r] * inv_den[qrow];
        }
    } else {
        // coalesced state store: [wv][mt][lane] float4
        #pragma unroll
        for (int mt = 0; mt < 8; ++mt) {
            float4 t = {accS[mt][0], accS[mt][1], accS[mt][2], accS[mt][3]};
            *(float4*)(stb + wv*2048 + mt*256 + lane*4) = t;
        }
        if (tid < 128) stb[16384 + tid] = Zl[tid];
    }
}

// Exclusive prefix over the 16 chunk states per chain; one thread per element column.
__global__ __launch_bounds__(256) void la_prefix(float* __restrict__ states) {
    const int gid = blockIdx.x * 256 + threadIdx.x;    // 0 .. 32*16512-1
    const int bh  = gid / STATE_SZ;
    const int e   = gid - bh * STATE_SZ;
    float* p = states + (size_t)bh * CHUNKS * STATE_SZ + e;
    float v[CHUNKS];
    #pragma unroll
    for (int c = 0; c < CHUNKS; ++c) v[c] = p[c * STATE_SZ];
    float run = 0.f;
    #pragma unroll
    for (int c = 0; c < CHUNKS; ++c) { p[c * STATE_SZ] = run; run += v[c]; }
}

extern "C" void kernel_launch(void* const* d_in, const int* in_sizes, int n_in,
                              void* d_out, int out_size, void* d_ws, size_t ws_size,
                              hipStream_t stream) {
    const float* Q     = (const float*)d_in[0];
    const float* K     = (const float*)d_in[1];
    const float* V     = (const float*)d_in[2];
    const float* scale = (const float*)d_in[3];
    const float* bias  = (const float*)d_in[4];
    float* out    = (float*)d_out;
    float* states = (float*)d_ws;   // 32*16*16512*4 = 33.8 MB

    hipLaunchKernelGGL((la_phase<false>), dim3(512), dim3(512), 0, stream,
                       Q, K, V, scale, bias, states, out);
    hipLaunchKernelGGL(la_prefix, dim3((32*STATE_SZ)/256), dim3(256), 0, stream, states);
    hipLaunchKernelGGL((la_phase<true>), dim3(512), dim3(512), 0, stream,
                       Q, K, V, scale, bias, states, out);
}